// Round 14
// baseline (68.486 us; speedup 1.0000x reference)
//
#include <hip/hip_runtime.h>
#include <hip/hip_bf16.h>
#include <math.h>

#define CC 512
#define HH 64
#define WW 96
#define NN 16
#define HW (HH*WW)        // 6144
#define NA 9
#define NLOC 36
#define NSC 18
#define NO_PAD 64         // 54 outputs padded to 64 (4 N-tiles of 16)

typedef __attribute__((ext_vector_type(4))) float f32x4;
typedef __attribute__((ext_vector_type(8))) short s16x8;

__device__ __forceinline__ unsigned short f2bf(float f) {
    __hip_bfloat16 h = __float2bfloat16(f);
    union { __hip_bfloat16 h; unsigned short u; } cv;
    cv.h = h;
    return cv.u;
}
__device__ __forceinline__ unsigned pk2(float lo, float hi) {
    return (unsigned)f2bf(lo) | ((unsigned)f2bf(hi) << 16);
}

// ---------------------------------------------------------------------------
// Kernel 1: weights -> bf16, padded to 64 rows. wbf[o][c], c contiguous.
// ---------------------------------------------------------------------------
__global__ void prep_w_kernel(const float* __restrict__ lw,
                              const float* __restrict__ sw,
                              unsigned short* __restrict__ wbf) {
    int i = blockIdx.x * 256 + threadIdx.x;   // over 64*512
    if (i >= NO_PAD * CC) return;
    int o = i >> 9, c = i & 511;
    float v = 0.0f;
    if (o < NLOC) v = lw[o * CC + c];
    else if (o < 54) v = sw[(o - NLOC) * CC + c];
    wbf[i] = f2bf(v);
}

// ---------------------------------------------------------------------------
// Kernel 2: barrier-free MFMA GEMM, 16 pos/wave -> 6144 waves = 24/CU target
// (TLP test: r13 proved 12 waves/CU leaves SIMDs ~90% idle while HBM sits at
// only ~5 of 6.3 TB/s). De-drained A+B register double-buffer kept from r13
// (compute set A while set B's loads are in flight -> counted vmcnt, never
// drains). No LDS, no barriers. __launch_bounds__(256,5): 102-VGPR cap fits
// acc(16)+A(2x8)+B(2x16)+addr (~85) -> prefetch survives regalloc.
// Grid = 1536 (%8==0), bijective XCD swizzle: each XCD streams a contiguous
// slab. A layout: row = lane&15 (position), k = (lane>>4)*8 + j.
// B layout: col = lane&15 (output o). C/D: col = o, row = (lane>>4)*4 + reg.
// Tail: 1536 blocks x 36 anchors = 55296 exactly.
// ---------------------------------------------------------------------------
__launch_bounds__(256, 5)
__global__ void rpn_mfma_kernel(const float* __restrict__ x,
                                const unsigned short* __restrict__ wbf,
                                const float* __restrict__ lb,
                                const float* __restrict__ sb,
                                float* __restrict__ out0,   // rpn_loc
                                float* __restrict__ out1,   // rpn_score
                                float* __restrict__ out2,   // rpn_fg_scores
                                float* __restrict__ out3) { // anchors
    const int tid  = threadIdx.x;
    const int lane = tid & 63;
    const int w    = tid >> 6;        // wave id
    const int col  = lane & 15;
    const int rgrp = lane >> 4;
    const int krow = rgrp * 8;        // lane's channel slice within a K-step

    // XCD-aware bijective swizzle: 1536 blocks, 8 XCDs, 192 contiguous each
    const int bid  = blockIdx.x;
    const int swz  = (bid & 7) * 192 + (bid >> 3);
    const int pbase = swz * 64;                 // 64 | HW -> single n per block
    const int n     = pbase / HW;
    const int rem   = pbase % HW;
    // lane's position column (wave w owns positions pbase+w*16 .. +16)
    const float* xA = x + (size_t)n * CC * HW + rem + w * 16 + col;
    const unsigned short* wB = wbf + (size_t)col * CC + krow;   // + nt*16*CC + kb

    f32x4 acc[4];
    #pragma unroll
    for (int nt = 0; nt < 4; ++nt) acc[nt] = (f32x4){0.f, 0.f, 0.f, 0.f};

    float aA[8], aB[8];
    s16x8 bA[4], bB[4];

    // ---- preload K-step 0 into set A ----
    #pragma unroll
    for (int j = 0; j < 8; ++j)
        aA[j] = xA[(size_t)(krow + j) * HW];
    #pragma unroll
    for (int nt = 0; nt < 4; ++nt)
        bA[nt] = *reinterpret_cast<const s16x8*>(wB + (size_t)nt * 16 * CC);

    #pragma unroll 1
    for (int ks = 0; ks < 16; ks += 2) {
        const int kb1 = (ks + 1) * 32;
        const int kb2 = (ks + 2) * 32;

        // issue K-step ks+1 into set B
        #pragma unroll
        for (int j = 0; j < 8; ++j)
            aB[j] = xA[(size_t)(kb1 + krow + j) * HW];
        #pragma unroll
        for (int nt = 0; nt < 4; ++nt)
            bB[nt] = *reinterpret_cast<const s16x8*>(
                wB + (size_t)nt * 16 * CC + kb1);

        // compute K-step ks from set A (waits only set-A regs -> counted vmcnt)
        {
            union { unsigned u[4]; s16x8 v; } fa;
            #pragma unroll
            for (int j = 0; j < 4; ++j) fa.u[j] = pk2(aA[2 * j], aA[2 * j + 1]);
            #pragma unroll
            for (int nt = 0; nt < 4; ++nt)
                acc[nt] = __builtin_amdgcn_mfma_f32_16x16x32_bf16(fa.v, bA[nt], acc[nt], 0, 0, 0);
        }

        // issue K-step ks+2 into set A
        if (ks < 14) {
            #pragma unroll
            for (int j = 0; j < 8; ++j)
                aA[j] = xA[(size_t)(kb2 + krow + j) * HW];
            #pragma unroll
            for (int nt = 0; nt < 4; ++nt)
                bA[nt] = *reinterpret_cast<const s16x8*>(
                    wB + (size_t)nt * 16 * CC + kb2);
        }

        // compute K-step ks+1 from set B
        {
            union { unsigned u[4]; s16x8 v; } fa;
            #pragma unroll
            for (int j = 0; j < 4; ++j) fa.u[j] = pk2(aB[2 * j], aB[2 * j + 1]);
            #pragma unroll
            for (int nt = 0; nt < 4; ++nt)
                acc[nt] = __builtin_amdgcn_mfma_f32_16x16x32_bf16(fa.v, bB[nt], acc[nt], 0, 0, 0);
        }
    }

    // ---- epilogue: bias + stores + fg softmax (score pairs in lanes l, l^1) ----
    #pragma unroll
    for (int nt = 0; nt < 4; ++nt) {
        int o = nt * 16 + col;
        float bias = (o < NLOC) ? lb[o] : ((o < 54) ? sb[o - NLOC] : 0.0f);
        #pragma unroll
        for (int r = 0; r < 4; ++r) {
            float val  = acc[nt][r] + bias;
            float part = __shfl_xor(val, 1);
            int p = pbase + w * 16 + rgrp * 4 + r;
            if (o < NLOC) {
                out0[(size_t)p * NLOC + o] = val;
            } else if (o < 54) {
                int os = o - NLOC;
                out1[(size_t)p * NSC + os] = val;
                if ((os & 1) == 0)
                    out2[(size_t)p * NA + (os >> 1)] = 1.0f / (1.0f + __expf(val - part));
            }
        }
    }

    // ---- tail: this block's 36-anchor slice (1536*36 = 55296 exactly) ----
    if (tid < 36) {
        int t = bid * 36 + tid;
        int a9   = t % NA;
        int rem2 = t / NA;
        int h = rem2 / WW, ww2 = rem2 % WW;
        int ri = a9 / 3, si = a9 % 3;
        const double ratios[3] = {0.5, 1.0, 2.0};
        const double scales[3] = {8.0, 16.0, 32.0};
        double ha = 16.0 * scales[si] * sqrt(ratios[ri]);
        double wa = 16.0 * scales[si] * sqrt(1.0 / ratios[ri]);
        float y1 = (float)(8.0 - ha * 0.5);
        float x1 = (float)(8.0 - wa * 0.5);
        float y2 = (float)(8.0 + ha * 0.5);
        float x2 = (float)(8.0 + wa * 0.5);
        float sy = (float)(h * 16);
        float sx = (float)(ww2 * 16);
        float4 v = make_float4(sy + y1, sx + x1, sy + y2, sx + x2);
        *reinterpret_cast<float4*>(out3 + (size_t)t * 4) = v;
    }
}

extern "C" void kernel_launch(void* const* d_in, const int* in_sizes, int n_in,
                              void* d_out, int out_size, void* d_ws, size_t ws_size,
                              hipStream_t stream) {
    const float* x  = (const float*)d_in[0];
    const float* lw = (const float*)d_in[1];
    const float* lb = (const float*)d_in[2];
    const float* sw = (const float*)d_in[3];
    const float* sb = (const float*)d_in[4];

    float* out0 = (float*)d_out;                          // (16, 55296, 4)
    float* out1 = out0 + (size_t)NN * HW * NLOC;          // (16, 64, 96, 18)
    float* out2 = out1 + (size_t)NN * HW * NSC;           // (16, 55296)
    float* out3 = out2 + (size_t)NN * HW * NA;            // (55296, 4)

    unsigned short* wbf = (unsigned short*)d_ws;          // 64*512*2 = 64 KB

    int grid_w = (NO_PAD * CC + 255) / 256;               // 128
    prep_w_kernel<<<grid_w, 256, 0, stream>>>(lw, sw, wbf);

    int grid_m = NN * HW / 64;                            // 1536
    rpn_mfma_kernel<<<grid_m, 256, 0, stream>>>(x, wbf, lb, sb, out0, out1, out2, out3);
}

// Round 15
// 68.372 us; speedup vs baseline: 1.0017x; 1.0017x over previous
//
#include <hip/hip_runtime.h>
#include <hip/hip_bf16.h>
#include <math.h>

#define CC 512
#define HH 64
#define WW 96
#define NN 16
#define HW (HH*WW)        // 6144
#define NA 9
#define NLOC 36
#define NSC 18
#define NO_PAD 64         // 54 outputs padded to 64 (4 N-tiles of 16)

typedef __attribute__((ext_vector_type(4))) float f32x4;
typedef __attribute__((ext_vector_type(8))) short s16x8;

__device__ __forceinline__ unsigned short f2bf(float f) {
    __hip_bfloat16 h = __float2bfloat16(f);
    union { __hip_bfloat16 h; unsigned short u; } cv;
    cv.h = h;
    return cv.u;
}
__device__ __forceinline__ unsigned pk2(float lo, float hi) {
    return (unsigned)f2bf(lo) | ((unsigned)f2bf(hi) << 16);
}

// ---------------------------------------------------------------------------
// Kernel 1: weights -> bf16, padded to 64 rows. wbf[o][c], c contiguous.
// ---------------------------------------------------------------------------
__global__ void prep_w_kernel(const float* __restrict__ lw,
                              const float* __restrict__ sw,
                              unsigned short* __restrict__ wbf) {
    int i = blockIdx.x * 256 + threadIdx.x;   // over 64*512
    if (i >= NO_PAD * CC) return;
    int o = i >> 9, c = i & 511;
    float v = 0.0f;
    if (o < NLOC) v = lw[o * CC + c];
    else if (o < 54) v = sw[(o - NLOC) * CC + c];
    wbf[i] = f2bf(v);
}

// ---------------------------------------------------------------------------
// Kernel 2: barrier-free MFMA GEMM, 16 pos/wave, grid 1536 -> 6144 waves.
// CLEAN TLP test vs r13 (12 waves/CU): __launch_bounds__(256,4) caps VGPR at
// 128, which FITS the de-drained A+B register double-buffer (~85 VGPR; the
// r14 (256,5) bound forced VGPR<=64 via the occupancy step granularity and
// regalloc serialized the pipeline -> that test was void, VGPR=40).
// At VGPR in (64,128]: 4 waves/SIMD = 16 waves/CU = +33% TLP over r13.
// De-drained ping-pong: compute set A while set B's loads are in flight ->
// counted vmcnt, never drains. No LDS, no barriers.
// Grid 1536 (%8==0), bijective XCD swizzle. A: row=lane&15 (pos),
// k=(lane>>4)*8+j. B: col=lane&15 (o). C/D: col=o, row=(lane>>4)*4+reg.
// Tail: 1536 blocks x 36 anchors = 55296 exactly.
// ---------------------------------------------------------------------------
__launch_bounds__(256, 4)
__global__ void rpn_mfma_kernel(const float* __restrict__ x,
                                const unsigned short* __restrict__ wbf,
                                const float* __restrict__ lb,
                                const float* __restrict__ sb,
                                float* __restrict__ out0,   // rpn_loc
                                float* __restrict__ out1,   // rpn_score
                                float* __restrict__ out2,   // rpn_fg_scores
                                float* __restrict__ out3) { // anchors
    const int tid  = threadIdx.x;
    const int lane = tid & 63;
    const int w    = tid >> 6;        // wave id
    const int col  = lane & 15;
    const int rgrp = lane >> 4;
    const int krow = rgrp * 8;        // lane's channel slice within a K-step

    // XCD-aware bijective swizzle: 1536 blocks, 8 XCDs, 192 contiguous each
    const int bid  = blockIdx.x;
    const int swz  = (bid & 7) * 192 + (bid >> 3);
    const int pbase = swz * 64;                 // 64 | HW -> single n per block
    const int n     = pbase / HW;
    const int rem   = pbase % HW;
    const float* xA = x + (size_t)n * CC * HW + rem + w * 16 + col;
    const unsigned short* wB = wbf + (size_t)col * CC + krow;   // + nt*16*CC + kb

    f32x4 acc[4];
    #pragma unroll
    for (int nt = 0; nt < 4; ++nt) acc[nt] = (f32x4){0.f, 0.f, 0.f, 0.f};

    float aA[8], aB[8];
    s16x8 bA[4], bB[4];

    // ---- preload K-step 0 into set A ----
    #pragma unroll
    for (int j = 0; j < 8; ++j)
        aA[j] = xA[(size_t)(krow + j) * HW];
    #pragma unroll
    for (int nt = 0; nt < 4; ++nt)
        bA[nt] = *reinterpret_cast<const s16x8*>(wB + (size_t)nt * 16 * CC);

    #pragma unroll 1
    for (int ks = 0; ks < 16; ks += 2) {
        const int kb1 = (ks + 1) * 32;
        const int kb2 = (ks + 2) * 32;

        // issue K-step ks+1 into set B
        #pragma unroll
        for (int j = 0; j < 8; ++j)
            aB[j] = xA[(size_t)(kb1 + krow + j) * HW];
        #pragma unroll
        for (int nt = 0; nt < 4; ++nt)
            bB[nt] = *reinterpret_cast<const s16x8*>(
                wB + (size_t)nt * 16 * CC + kb1);

        // compute K-step ks from set A (waits only set-A regs -> counted vmcnt)
        {
            union { unsigned u[4]; s16x8 v; } fa;
            #pragma unroll
            for (int j = 0; j < 4; ++j) fa.u[j] = pk2(aA[2 * j], aA[2 * j + 1]);
            #pragma unroll
            for (int nt = 0; nt < 4; ++nt)
                acc[nt] = __builtin_amdgcn_mfma_f32_16x16x32_bf16(fa.v, bA[nt], acc[nt], 0, 0, 0);
        }

        // issue K-step ks+2 into set A
        if (ks < 14) {
            #pragma unroll
            for (int j = 0; j < 8; ++j)
                aA[j] = xA[(size_t)(kb2 + krow + j) * HW];
            #pragma unroll
            for (int nt = 0; nt < 4; ++nt)
                bA[nt] = *reinterpret_cast<const s16x8*>(
                    wB + (size_t)nt * 16 * CC + kb2);
        }

        // compute K-step ks+1 from set B
        {
            union { unsigned u[4]; s16x8 v; } fa;
            #pragma unroll
            for (int j = 0; j < 4; ++j) fa.u[j] = pk2(aB[2 * j], aB[2 * j + 1]);
            #pragma unroll
            for (int nt = 0; nt < 4; ++nt)
                acc[nt] = __builtin_amdgcn_mfma_f32_16x16x32_bf16(fa.v, bB[nt], acc[nt], 0, 0, 0);
        }
    }

    // ---- epilogue: bias + stores + fg softmax (score pairs in lanes l, l^1) ----
    #pragma unroll
    for (int nt = 0; nt < 4; ++nt) {
        int o = nt * 16 + col;
        float bias = (o < NLOC) ? lb[o] : ((o < 54) ? sb[o - NLOC] : 0.0f);
        #pragma unroll
        for (int r = 0; r < 4; ++r) {
            float val  = acc[nt][r] + bias;
            float part = __shfl_xor(val, 1);
            int p = pbase + w * 16 + rgrp * 4 + r;
            if (o < NLOC) {
                out0[(size_t)p * NLOC + o] = val;
            } else if (o < 54) {
                int os = o - NLOC;
                out1[(size_t)p * NSC + os] = val;
                if ((os & 1) == 0)
                    out2[(size_t)p * NA + (os >> 1)] = 1.0f / (1.0f + __expf(val - part));
            }
        }
    }

    // ---- tail: this block's 36-anchor slice (1536*36 = 55296 exactly) ----
    if (tid < 36) {
        int t = bid * 36 + tid;
        int a9   = t % NA;
        int rem2 = t / NA;
        int h = rem2 / WW, ww2 = rem2 % WW;
        int ri = a9 / 3, si = a9 % 3;
        const double ratios[3] = {0.5, 1.0, 2.0};
        const double scales[3] = {8.0, 16.0, 32.0};
        double ha = 16.0 * scales[si] * sqrt(ratios[ri]);
        double wa = 16.0 * scales[si] * sqrt(1.0 / ratios[ri]);
        float y1 = (float)(8.0 - ha * 0.5);
        float x1 = (float)(8.0 - wa * 0.5);
        float y2 = (float)(8.0 + ha * 0.5);
        float x2 = (float)(8.0 + wa * 0.5);
        float sy = (float)(h * 16);
        float sx = (float)(ww2 * 16);
        float4 v = make_float4(sy + y1, sx + x1, sy + y2, sx + x2);
        *reinterpret_cast<float4*>(out3 + (size_t)t * 4) = v;
    }
}

extern "C" void kernel_launch(void* const* d_in, const int* in_sizes, int n_in,
                              void* d_out, int out_size, void* d_ws, size_t ws_size,
                              hipStream_t stream) {
    const float* x  = (const float*)d_in[0];
    const float* lw = (const float*)d_in[1];
    const float* lb = (const float*)d_in[2];
    const float* sw = (const float*)d_in[3];
    const float* sb = (const float*)d_in[4];

    float* out0 = (float*)d_out;                          // (16, 55296, 4)
    float* out1 = out0 + (size_t)NN * HW * NLOC;          // (16, 64, 96, 18)
    float* out2 = out1 + (size_t)NN * HW * NSC;           // (16, 55296)
    float* out3 = out2 + (size_t)NN * HW * NA;            // (55296, 4)

    unsigned short* wbf = (unsigned short*)d_ws;          // 64*512*2 = 64 KB

    int grid_w = (NO_PAD * CC + 255) / 256;               // 128
    prep_w_kernel<<<grid_w, 256, 0, stream>>>(lw, sw, wbf);

    int grid_m = NN * HW / 64;                            // 1536
    rpn_mfma_kernel<<<grid_m, 256, 0, stream>>>(x, wbf, lb, sb, out0, out1, out2, out3);
}

// Round 16
// 50.918 us; speedup vs baseline: 1.3450x; 1.3428x over previous
//
#include <hip/hip_runtime.h>
#include <hip/hip_bf16.h>
#include <math.h>

#define CC 512
#define HH 64
#define WW 96
#define NN 16
#define HW (HH*WW)        // 6144
#define NA 9
#define NLOC 36
#define NSC 18
#define NO_PAD 64         // 54 outputs padded to 64 (4 N-tiles of 16)

typedef __attribute__((ext_vector_type(4))) float f32x4;
typedef __attribute__((ext_vector_type(2))) float f32x2;
typedef __attribute__((ext_vector_type(8))) short s16x8;

__device__ __forceinline__ unsigned short f2bf(float f) {
    __hip_bfloat16 h = __float2bfloat16(f);
    union { __hip_bfloat16 h; unsigned short u; } cv;
    cv.h = h;
    return cv.u;
}
__device__ __forceinline__ unsigned pk2(float lo, float hi) {
    return (unsigned)f2bf(lo) | ((unsigned)f2bf(hi) << 16);
}

// ---------------------------------------------------------------------------
// Kernel 1: weights -> bf16, padded to 64 rows. wbf[o][c], c contiguous.
// ---------------------------------------------------------------------------
__global__ void prep_w_kernel(const float* __restrict__ lw,
                              const float* __restrict__ sw,
                              unsigned short* __restrict__ wbf) {
    int i = blockIdx.x * 256 + threadIdx.x;   // over 64*512
    if (i >= NO_PAD * CC) return;
    int o = i >> 9, c = i & 511;
    float v = 0.0f;
    if (o < NLOC) v = lw[o * CC + c];
    else if (o < 54) v = sw[(o - NLOC) * CC + c];
    wbf[i] = f2bf(v);
}

// ---------------------------------------------------------------------------
// Kernel 2 (= round-13 best, 50.8 us): barrier-free MFMA GEMM, M_rep=2
// (even/odd positions), BOTH A and B double-buffered in registers so the
// MFMA waits are counted vmcnt (never drain the prefetch). Block = 4
// independent waves x 32-pos windows; A-load = float2 per lane (full 128B
// lines). Grid = 768 = 3 blocks/CU; bijective XCD swizzle (768%8==0).
// A layout: row = lane&15 (pos pair), k = (lane>>4)*8 + j.
// B layout: col = lane&15 (output o). C/D: col = o, row = (lane>>4)*4 + reg;
// row r of tile m -> global position pbase + w*32 + 2*row + m.
// Achieves ~4.9 TB/s effective delivery (~78% of achievable streaming
// ceiling); width/depth/TLP/drain levers all tested null beyond this.
// ---------------------------------------------------------------------------
__launch_bounds__(256, 3)
__global__ void rpn_mfma_kernel(const float* __restrict__ x,
                                const unsigned short* __restrict__ wbf,
                                const float* __restrict__ lb,
                                const float* __restrict__ sb,
                                float* __restrict__ out0,   // rpn_loc
                                float* __restrict__ out1,   // rpn_score
                                float* __restrict__ out2,   // rpn_fg_scores
                                float* __restrict__ out3) { // anchors
    const int tid  = threadIdx.x;
    const int lane = tid & 63;
    const int w    = tid >> 6;        // wave id
    const int col  = lane & 15;
    const int rgrp = lane >> 4;
    const int krow = rgrp * 8;        // lane's channel slice within a K-step

    // XCD-aware bijective swizzle: 768 blocks, 8 XCDs, 96 contiguous each
    const int bid  = blockIdx.x;
    const int swz  = (bid & 7) * 96 + (bid >> 3);
    const int pbase = swz * 128;                // 128 | HW -> single n per block
    const int n     = pbase / HW;
    const int rem   = pbase % HW;
    const float* xA = x + (size_t)n * CC * HW + rem + w * 32 + 2 * col;
    const unsigned short* wB = wbf + (size_t)col * CC + krow;   // + nt*16*CC + kb

    f32x4 acc0[4], acc1[4];
    #pragma unroll
    for (int nt = 0; nt < 4; ++nt) {
        acc0[nt] = (f32x4){0.f, 0.f, 0.f, 0.f};
        acc1[nt] = (f32x4){0.f, 0.f, 0.f, 0.f};
    }

    f32x2 aA[8], aB[8];
    s16x8 bA[4], bB[4];

    // ---- preload K-step 0 into set A ----
    #pragma unroll
    for (int j = 0; j < 8; ++j)
        aA[j] = *reinterpret_cast<const f32x2*>(xA + (size_t)(krow + j) * HW);
    #pragma unroll
    for (int nt = 0; nt < 4; ++nt)
        bA[nt] = *reinterpret_cast<const s16x8*>(wB + (size_t)nt * 16 * CC);

    #pragma unroll 1
    for (int ks = 0; ks < 16; ks += 2) {
        const int kb1 = (ks + 1) * 32;
        const int kb2 = (ks + 2) * 32;

        // issue K-step ks+1 into set B (ks+1 <= 15 always)
        #pragma unroll
        for (int j = 0; j < 8; ++j)
            aB[j] = *reinterpret_cast<const f32x2*>(
                xA + (size_t)(kb1 + krow + j) * HW);
        #pragma unroll
        for (int nt = 0; nt < 4; ++nt)
            bB[nt] = *reinterpret_cast<const s16x8*>(
                wB + (size_t)nt * 16 * CC + kb1);

        // compute K-step ks from set A (waits only on set-A regs -> counted vmcnt)
        {
            union { unsigned u[4]; s16x8 v; } fa0, fa1;
            #pragma unroll
            for (int j = 0; j < 4; ++j) {
                fa0.u[j] = pk2(aA[2 * j].x, aA[2 * j + 1].x);
                fa1.u[j] = pk2(aA[2 * j].y, aA[2 * j + 1].y);
            }
            #pragma unroll
            for (int nt = 0; nt < 4; ++nt)
                acc0[nt] = __builtin_amdgcn_mfma_f32_16x16x32_bf16(fa0.v, bA[nt], acc0[nt], 0, 0, 0);
            #pragma unroll
            for (int nt = 0; nt < 4; ++nt)
                acc1[nt] = __builtin_amdgcn_mfma_f32_16x16x32_bf16(fa1.v, bA[nt], acc1[nt], 0, 0, 0);
        }

        // issue K-step ks+2 into set A
        if (ks < 14) {
            #pragma unroll
            for (int j = 0; j < 8; ++j)
                aA[j] = *reinterpret_cast<const f32x2*>(
                    xA + (size_t)(kb2 + krow + j) * HW);
            #pragma unroll
            for (int nt = 0; nt < 4; ++nt)
                bA[nt] = *reinterpret_cast<const s16x8*>(
                    wB + (size_t)nt * 16 * CC + kb2);
        }

        // compute K-step ks+1 from set B
        {
            union { unsigned u[4]; s16x8 v; } fa0, fa1;
            #pragma unroll
            for (int j = 0; j < 4; ++j) {
                fa0.u[j] = pk2(aB[2 * j].x, aB[2 * j + 1].x);
                fa1.u[j] = pk2(aB[2 * j].y, aB[2 * j + 1].y);
            }
            #pragma unroll
            for (int nt = 0; nt < 4; ++nt)
                acc0[nt] = __builtin_amdgcn_mfma_f32_16x16x32_bf16(fa0.v, bB[nt], acc0[nt], 0, 0, 0);
            #pragma unroll
            for (int nt = 0; nt < 4; ++nt)
                acc1[nt] = __builtin_amdgcn_mfma_f32_16x16x32_bf16(fa1.v, bB[nt], acc1[nt], 0, 0, 0);
        }
    }

    // ---- epilogue: bias + stores + fg softmax (score pairs in lanes l, l^1) ----
    #pragma unroll
    for (int m = 0; m < 2; ++m) {
        #pragma unroll
        for (int nt = 0; nt < 4; ++nt) {
            int o = nt * 16 + col;
            float bias = (o < NLOC) ? lb[o] : ((o < 54) ? sb[o - NLOC] : 0.0f);
            #pragma unroll
            for (int r = 0; r < 4; ++r) {
                float val  = (m == 0 ? acc0[nt][r] : acc1[nt][r]) + bias;
                float part = __shfl_xor(val, 1);
                int pgl = pbase + w * 32 + 2 * (rgrp * 4 + r) + m;   // even/odd
                if (o < NLOC) {
                    out0[(size_t)pgl * NLOC + o] = val;
                } else if (o < 54) {
                    int os = o - NLOC;
                    out1[(size_t)pgl * NSC + os] = val;
                    if ((os & 1) == 0)
                        out2[(size_t)pgl * NA + (os >> 1)] = 1.0f / (1.0f + __expf(val - part));
                }
            }
        }
    }

    // ---- tail: this block's 72-anchor slice (768*72 = 55296 exactly) ----
    if (tid < 72) {
        int t = bid * 72 + tid;
        int a9   = t % NA;
        int rem2 = t / NA;
        int h = rem2 / WW, ww2 = rem2 % WW;
        int ri = a9 / 3, si = a9 % 3;
        const double ratios[3] = {0.5, 1.0, 2.0};
        const double scales[3] = {8.0, 16.0, 32.0};
        double ha = 16.0 * scales[si] * sqrt(ratios[ri]);
        double wa = 16.0 * scales[si] * sqrt(1.0 / ratios[ri]);
        float y1 = (float)(8.0 - ha * 0.5);
        float x1 = (float)(8.0 - wa * 0.5);
        float y2 = (float)(8.0 + ha * 0.5);
        float x2 = (float)(8.0 + wa * 0.5);
        float sy = (float)(h * 16);
        float sx = (float)(ww2 * 16);
        float4 v = make_float4(sy + y1, sx + x1, sy + y2, sx + x2);
        *reinterpret_cast<float4*>(out3 + (size_t)t * 4) = v;
    }
}

extern "C" void kernel_launch(void* const* d_in, const int* in_sizes, int n_in,
                              void* d_out, int out_size, void* d_ws, size_t ws_size,
                              hipStream_t stream) {
    const float* x  = (const float*)d_in[0];
    const float* lw = (const float*)d_in[1];
    const float* lb = (const float*)d_in[2];
    const float* sw = (const float*)d_in[3];
    const float* sb = (const float*)d_in[4];

    float* out0 = (float*)d_out;                          // (16, 55296, 4)
    float* out1 = out0 + (size_t)NN * HW * NLOC;          // (16, 64, 96, 18)
    float* out2 = out1 + (size_t)NN * HW * NSC;           // (16, 55296)
    float* out3 = out2 + (size_t)NN * HW * NA;            // (55296, 4)

    unsigned short* wbf = (unsigned short*)d_ws;          // 64*512*2 = 64 KB

    int grid_w = (NO_PAD * CC + 255) / 256;               // 128
    prep_w_kernel<<<grid_w, 256, 0, stream>>>(lw, sw, wbf);

    int grid_m = NN * HW / 128;                           // 768
    rpn_mfma_kernel<<<grid_m, 256, 0, stream>>>(x, wbf, lb, sb, out0, out1, out2, out3);
}